// Round 17
// baseline (96.166 us; speedup 1.0000x reference)
//
#include <hip/hip_runtime.h>

#define D_MODEL 512
#define D4C     128
#define DA_C    256
#define FACTOR_ 128
#define BS_     4096
#define WIN_    4096

typedef __attribute__((ext_vector_type(8))) short short8;
typedef __attribute__((ext_vector_type(4))) float f32x4;

__device__ __forceinline__ float wave_reduce_sum(float x) {
#pragma unroll
  for (int o = 32; o; o >>= 1) x += __shfl_xor(x, o, 64);
  return x;
}
__device__ __forceinline__ int wave_reduce_sum_i(int x) {
#pragma unroll
  for (int o = 32; o; o >>= 1) x += __shfl_xor(x, o, 64);
  return x;
}
__device__ __forceinline__ unsigned short f2bf(float f) {
  unsigned u = __float_as_uint(f);
  unsigned r = (u + 0x7FFF + ((u >> 16) & 1)) >> 16;   // RNE
  return (unsigned short)r;
}

// ---- L1: prep (3 windowed sorts + vvec + W bf16 casts), ONE launch (r16 verbatim) ----
__global__ __launch_bounds__(1024)
void prep_all_kernel(const int* __restrict__ seg1, int n1, int k1,
                     int* __restrict__ offs1, int* __restrict__ perm1,
                     const int* __restrict__ seg2, int n2, int k2,
                     int* __restrict__ offs2, int* __restrict__ perm2,
                     const int* __restrict__ seg3, int n3, int k3,
                     int* __restrict__ offs3, int* __restrict__ perm3,
                     const float* __restrict__ Ws01, const float* __restrict__ ws02,
                     const float* __restrict__ Ws1,  const float* __restrict__ ws2,
                     float* __restrict__ v0, float* __restrict__ v1,
                     const float* __restrict__ user_W, const float* __restrict__ item_W,
                     unsigned short* __restrict__ uW_h, unsigned short* __restrict__ iW_h,
                     int nw1) {
  __shared__ int hist[WIN_];
  __shared__ int obase[WIN_];
  __shared__ int wpre[17];
  __shared__ int below_sh[16];
  __shared__ float vred[8][128];

  const int bx = blockIdx.x, t = threadIdx.x;
  const int lane = t & 63, wid = t >> 6;
  const int nsort = nw1 + 2;

  if (bx < nsort) {
    const int* seg; int n, k, lo, hi;
    int *offs, *perm;
    if (bx < nw1)      { seg = seg1; n = n1; k = k1; offs = offs1; perm = perm1;
                         lo = bx * WIN_; hi = min(lo + WIN_, k); }
    else if (bx == nw1){ seg = seg2; n = n2; k = k2; offs = offs2; perm = perm2;
                         lo = 0; hi = k; }
    else               { seg = seg3; n = n3; k = k3; offs = offs3; perm = perm3;
                         lo = 0; hi = k; }
    const int wk = hi - lo;
    const int n4 = n >> 2;
    const int4* __restrict__ seg4 = (const int4*)seg;

    for (int i = t; i < wk; i += 1024) hist[i] = 0;
    __syncthreads();

    int below = 0;
#pragma unroll 4
    for (int i = t; i < n4; i += 1024) {
      int4 v = seg4[i];
      unsigned a = (unsigned)v.x, b = (unsigned)v.y,
               c = (unsigned)v.z, d = (unsigned)v.w;
      if (a < (unsigned)lo) below++;
      else { unsigned l = a - (unsigned)lo; if (l < (unsigned)wk) atomicAdd(&hist[l], 1); }
      if (b < (unsigned)lo) below++;
      else { unsigned l = b - (unsigned)lo; if (l < (unsigned)wk) atomicAdd(&hist[l], 1); }
      if (c < (unsigned)lo) below++;
      else { unsigned l = c - (unsigned)lo; if (l < (unsigned)wk) atomicAdd(&hist[l], 1); }
      if (d < (unsigned)lo) below++;
      else { unsigned l = d - (unsigned)lo; if (l < (unsigned)wk) atomicAdd(&hist[l], 1); }
    }
    for (int i = n4 * 4 + t; i < n; i += 1024) {
      unsigned uv = (unsigned)seg[i];
      if (uv < (unsigned)lo) below++;
      else { unsigned l = uv - (unsigned)lo;
             if (l < (unsigned)wk) atomicAdd(&hist[l], 1); }
    }
    below = wave_reduce_sum_i(below);
    if (lane == 0) below_sh[wid] = below;
    __syncthreads();
    int base = 0;
#pragma unroll
    for (int i = 0; i < 16; ++i) base += below_sh[i];

    const int per = (wk + 1023) / 1024;
    const int slo = min(t * per, wk), shi = min(slo + per, wk);
    int s = 0;
    for (int i = slo; i < shi; ++i) s += hist[i];
    int x = s;
#pragma unroll
    for (int o = 1; o < 64; o <<= 1) {
      int y = __shfl_up(x, o, 64);
      if (lane >= o) x += y;
    }
    if (lane == 63) wpre[wid] = x;
    __syncthreads();
    if (t == 0) {
      int acc = 0;
#pragma unroll
      for (int i = 0; i < 16; ++i) { int tmp = wpre[i]; wpre[i] = acc; acc += tmp; }
      wpre[16] = acc;
    }
    __syncthreads();
    int acc = base + wpre[wid] + (x - s);
    for (int i = slo; i < shi; ++i) {
      obase[i] = acc;
      offs[lo + i] = acc;
      acc += hist[i];
    }
    if (hi == k && t == 0) offs[k] = base + wpre[16];
    __syncthreads();

    for (int i = t; i < wk; i += 1024) hist[i] = 0;
    __syncthreads();
#pragma unroll 4
    for (int i = t; i < n4; i += 1024) {
      int4 v = seg4[i];
      const int rbase = i * 4;
      { unsigned l = (unsigned)v.x - (unsigned)lo;
        if (l < (unsigned)wk) { int pos = atomicAdd(&hist[l], 1); perm[obase[l] + pos] = rbase; } }
      { unsigned l = (unsigned)v.y - (unsigned)lo;
        if (l < (unsigned)wk) { int pos = atomicAdd(&hist[l], 1); perm[obase[l] + pos] = rbase + 1; } }
      { unsigned l = (unsigned)v.z - (unsigned)lo;
        if (l < (unsigned)wk) { int pos = atomicAdd(&hist[l], 1); perm[obase[l] + pos] = rbase + 2; } }
      { unsigned l = (unsigned)v.w - (unsigned)lo;
        if (l < (unsigned)wk) { int pos = atomicAdd(&hist[l], 1); perm[obase[l] + pos] = rbase + 3; } }
    }
    for (int i = n4 * 4 + t; i < n; i += 1024) {
      unsigned l = (unsigned)seg[i] - (unsigned)lo;
      if ((unsigned)seg[i] >= (unsigned)lo && l < (unsigned)wk) {
        int pos = atomicAdd(&hist[l], 1);
        perm[obase[l] + pos] = i;
      }
    }
    return;
  }

  if (bx < nsort + 8) {
    const int vb = bx - nsort;
    const int m = vb >> 2;
    const int c0 = (vb & 3) * 128;
    const float* W  = m ? Ws1 : Ws01;
    const float* w2 = m ? ws2 : ws02;
    const int col = t & 127;
    const int g = t >> 7;
    float s = 0.f;
    for (int a = g * 32; a < g * 32 + 32; ++a)
      s += w2[a] * W[a * D_MODEL + c0 + col];
    vred[g][col] = s;
    __syncthreads();
    if (t < 128) {
      float acc = 0.f;
#pragma unroll
      for (int q = 0; q < 8; ++q) acc += vred[q][t];
      (m ? v1 : v0)[c0 + t] = acc;
    }
    return;
  }

  {
    const int w = bx - (nsort + 8);
    const float4* __restrict__ src = (const float4*)(w ? item_W : user_W);
    ushort4* __restrict__ dst = (ushort4*)(w ? iW_h : uW_h);
    for (int i = t; i < FACTOR_ * D_MODEL / 4; i += 1024) {
      float4 v = src[i];
      ushort4 h;
      h.x = f2bf(v.x); h.y = f2bf(v.y); h.z = f2bf(v.z); h.w = f2bf(v.w);
      dst[i] = h;
    }
  }
}

// Pool one segment (wave gather; VALIDATED r7-r16) + optional bf16 copy.
__device__ __forceinline__ void pool_one(const float* __restrict__ X,
                                         const int* __restrict__ perm,
                                         const int* __restrict__ offs, int g, int lane,
                                         float4 va, float4 vb, float* __restrict__ out,
                                         int orow, unsigned short* __restrict__ hout) {
  const float4* __restrict__ X4 = (const float4*)X;
  const int s = offs[g], e = offs[g + 1];
  float4 a0 = make_float4(0.f, 0.f, 0.f, 0.f);
  float4 a1 = make_float4(0.f, 0.f, 0.f, 0.f);
  float z = 0.f;
  for (int p = s; p < e; ++p) {
    int row = perm[p];
    float4 x0 = X4[(size_t)row * D4C + lane * 2];
    float4 x1 = X4[(size_t)row * D4C + lane * 2 + 1];
    float d = x0.x * va.x + x0.y * va.y + x0.z * va.z + x0.w * va.w
            + x1.x * vb.x + x1.y * vb.y + x1.z * vb.z + x1.w * vb.w;
    d = wave_reduce_sum(d);
    float w = expf(d);
    z += w;
    a0.x += w * x0.x; a0.y += w * x0.y; a0.z += w * x0.z; a0.w += w * x0.w;
    a1.x += w * x1.x; a1.y += w * x1.y; a1.z += w * x1.z; a1.w += w * x1.w;
  }
  float inv = (z > 0.f) ? 1.0f / z : 0.f;
  a0.x *= inv; a0.y *= inv; a0.z *= inv; a0.w *= inv;
  a1.x *= inv; a1.y *= inv; a1.z *= inv; a1.w *= inv;
  float4* __restrict__ O4 = (float4*)out;
  O4[(size_t)orow * D4C + lane * 2]     = a0;
  O4[(size_t)orow * D4C + lane * 2 + 1] = a1;
  if (hout) {
    ushort4 h0, h1;
    h0.x = f2bf(a0.x); h0.y = f2bf(a0.y); h0.z = f2bf(a0.z); h0.w = f2bf(a0.w);
    h1.x = f2bf(a1.x); h1.y = f2bf(a1.y); h1.z = f2bf(a1.z); h1.w = f2bf(a1.w);
    ((ushort4*)hout)[(size_t)orow * D4C + lane * 2]     = h0;
    ((ushort4*)hout)[(size_t)orow * D4C + lane * 2 + 1] = h1;
  }
}

// ---- L2: mega pool — role A now 8 waves/block (1 uni-row per wave) ----
__global__ __launch_bounds__(512)
void mega_pool_kernel(const float* __restrict__ pieces,
                      const int* __restrict__ perm1, const int* __restrict__ offs1,
                      const int* __restrict__ perm2, const int* __restrict__ offs2,
                      const int* __restrict__ user_seg, int n_uni,
                      const float* __restrict__ itemj_piece,
                      const int* __restrict__ permj, const int* __restrict__ offsj,
                      const float* __restrict__ v0, const float* __restrict__ v1,
                      unsigned short* __restrict__ urep_h,
                      unsigned short* __restrict__ itemi_h,
                      unsigned short* __restrict__ itemj_h,
                      float* __restrict__ itemi_out, float* __restrict__ itemj_out,
                      const int* __restrict__ pos_ptr) {
  const int bx = blockIdx.x;
  const int t = threadIdx.x;
  const int wid = t >> 6, lane = t & 63;
  const float4* __restrict__ V0 = (const float4*)v0;

  if (bx < BS_) {
    const float4* __restrict__ V1 = (const float4*)v1;
    const float4* __restrict__ X4 = (const float4*)pieces;
    float4 va0 = V0[lane * 2], vb0 = V0[lane * 2 + 1];
    float4 va1 = V1[lane * 2], vb1 = V1[lane * 2 + 1];
    int pos = *pos_ptr;
    pos = min(max(pos, 0), n_uni - BS_);
    const int u = bx;
    const int s2 = offs2[u], e2 = offs2[u + 1];

    float4 acc0 = make_float4(0.f, 0.f, 0.f, 0.f);
    float4 acc1 = make_float4(0.f, 0.f, 0.f, 0.f);
    float zz = 0.f;
    for (int k = s2 + wid; k < e2; k += 8) {      // 8 waves: 1 row/wave typical
      const int rr = perm2[k];
      const int s1 = offs1[rr], e1 = offs1[rr + 1];
      float4 r0 = make_float4(0.f, 0.f, 0.f, 0.f);
      float4 r1 = make_float4(0.f, 0.f, 0.f, 0.f);
      float z1 = 0.f;
      for (int p = s1; p < e1; ++p) {
        int prow = perm1[p];
        float4 x0 = X4[(size_t)prow * D4C + lane * 2];
        float4 x1 = X4[(size_t)prow * D4C + lane * 2 + 1];
        float d = x0.x * va0.x + x0.y * va0.y + x0.z * va0.z + x0.w * va0.w
                + x1.x * vb0.x + x1.y * vb0.y + x1.z * vb0.z + x1.w * vb0.w;
        d = wave_reduce_sum(d);
        float w = expf(d);
        z1 += w;
        r0.x += w * x0.x; r0.y += w * x0.y; r0.z += w * x0.z; r0.w += w * x0.w;
        r1.x += w * x1.x; r1.y += w * x1.y; r1.z += w * x1.z; r1.w += w * x1.w;
      }
      float inv1 = (z1 > 0.f) ? 1.0f / z1 : 0.f;
      r0.x *= inv1; r0.y *= inv1; r0.z *= inv1; r0.w *= inv1;
      r1.x *= inv1; r1.y *= inv1; r1.z *= inv1; r1.w *= inv1;
      if (rr >= pos && rr < pos + BS_) {
        float4* __restrict__ O2 = (float4*)itemi_out;
        O2[(size_t)(rr - pos) * D4C + lane * 2]     = r0;
        O2[(size_t)(rr - pos) * D4C + lane * 2 + 1] = r1;
        ushort4 h0, h1;
        h0.x = f2bf(r0.x); h0.y = f2bf(r0.y); h0.z = f2bf(r0.z); h0.w = f2bf(r0.w);
        h1.x = f2bf(r1.x); h1.y = f2bf(r1.y); h1.z = f2bf(r1.z); h1.w = f2bf(r1.w);
        ((ushort4*)itemi_h)[(size_t)(rr - pos) * D4C + lane * 2]     = h0;
        ((ushort4*)itemi_h)[(size_t)(rr - pos) * D4C + lane * 2 + 1] = h1;
      }
      float d1 = r0.x * va1.x + r0.y * va1.y + r0.z * va1.z + r0.w * va1.w
               + r1.x * vb1.x + r1.y * vb1.y + r1.z * vb1.z + r1.w * vb1.w;
      d1 = wave_reduce_sum(d1);
      float e2w = expf(d1);
      zz += e2w;
      acc0.x += e2w * r0.x; acc0.y += e2w * r0.y;
      acc0.z += e2w * r0.z; acc0.w += e2w * r0.w;
      acc1.x += e2w * r1.x; acc1.y += e2w * r1.y;
      acc1.z += e2w * r1.z; acc1.w += e2w * r1.w;
    }
    __shared__ float4 pbuf[8][130];
    __shared__ float zbuf[8];
    pbuf[wid][lane * 2]     = acc0;
    pbuf[wid][lane * 2 + 1] = acc1;
    if (lane == 0) zbuf[wid] = zz;
    __syncthreads();
    if (wid == 0) {
      float4 A0 = make_float4(0.f, 0.f, 0.f, 0.f);
      float4 A1 = make_float4(0.f, 0.f, 0.f, 0.f);
      float Z = 0.f;
#pragma unroll
      for (int w = 0; w < 8; ++w) Z += zbuf[w];
#pragma unroll
      for (int w = 0; w < 8; ++w) {
        float4 p0 = pbuf[w][lane * 2], p1 = pbuf[w][lane * 2 + 1];
        A0.x += p0.x; A0.y += p0.y; A0.z += p0.z; A0.w += p0.w;
        A1.x += p1.x; A1.y += p1.y; A1.z += p1.z; A1.w += p1.w;
      }
      float inv = (Z > 0.f) ? 1.0f / Z : 0.f;
      A0.x *= inv; A0.y *= inv; A0.z *= inv; A0.w *= inv;
      A1.x *= inv; A1.y *= inv; A1.z *= inv; A1.w *= inv;
      ushort4 h0, h1;
      h0.x = f2bf(A0.x); h0.y = f2bf(A0.y); h0.z = f2bf(A0.z); h0.w = f2bf(A0.w);
      h1.x = f2bf(A1.x); h1.y = f2bf(A1.y); h1.z = f2bf(A1.z); h1.w = f2bf(A1.w);
      ((ushort4*)urep_h)[(size_t)u * D4C + lane * 2]     = h0;
      ((ushort4*)urep_h)[(size_t)u * D4C + lane * 2 + 1] = h1;
    }
    return;
  }

  const int gridB = (BS_ + 7) >> 3;    // 8 segments per 512-thread block
  float4 va = V0[lane * 2], vb = V0[lane * 2 + 1];
  if (bx < BS_ + gridB) {
    int g = (bx - BS_) * 8 + wid;
    if (g >= BS_) return;
    pool_one(itemj_piece, permj, offsj, g, lane, va, vb, itemj_out, g, itemj_h);
  } else {
    int idx = (bx - BS_ - gridB) * 8 + wid;
    if (idx >= BS_) return;
    int pos = *pos_ptr;
    pos = min(max(pos, 0), n_uni - BS_);
    int rr = pos + idx;
    if ((unsigned)user_seg[rr] < (unsigned)BS_) return;
    pool_one(pieces, perm1, offs1, rr, lane, va, vb, itemi_out, idx, itemi_h);
  }
}

// ---- L3: MFMA latents + BPR scores (VALIDATED r16, verbatim) ----
__global__ __launch_bounds__(256)
void latpred_mfma_kernel(const unsigned short* __restrict__ urep_h,
                         const unsigned short* __restrict__ itemi_h,
                         const unsigned short* __restrict__ itemj_h,
                         const unsigned short* __restrict__ uW_h,
                         const unsigned short* __restrict__ iW_h,
                         const float* __restrict__ user_b,
                         const float* __restrict__ item_b,
                         float* __restrict__ pred_i, float* __restrict__ pred_j) {
  __shared__ float lats[3][16][132];
  const int rowbase = blockIdx.x * 16;
  const int t = threadIdx.x;
  const int wave = t >> 6, lane = t & 63;
  const int sel = lane & 15;
  const int kgrp = lane >> 4;

#pragma unroll
  for (int jj = 0; jj < 6; ++jj) {
    const int job = wave * 6 + jj;
    const int mat = job >> 3;
    const int ftile = job & 7;
    const unsigned short* A = mat == 0 ? urep_h : (mat == 1 ? itemi_h : itemj_h);
    const unsigned short* W = mat == 0 ? uW_h : iW_h;
    const float* b = mat == 0 ? user_b : item_b;
    const int f = ftile * 16 + sel;
    const short8* __restrict__ Arow = (const short8*)(A + (size_t)(rowbase + sel) * D_MODEL);
    const short8* __restrict__ Wrow = (const short8*)(W + (size_t)f * D_MODEL);
    f32x4 acc = {0.f, 0.f, 0.f, 0.f};
#pragma unroll
    for (int ks = 0; ks < 16; ++ks) {
      short8 af = Arow[ks * 4 + kgrp];
      short8 bf = Wrow[ks * 4 + kgrp];
      acc = __builtin_amdgcn_mfma_f32_16x16x32_bf16(af, bf, acc, 0, 0, 0);
    }
    const float bias = b[f];
    const int orow0 = kgrp * 4;
#pragma unroll
    for (int j = 0; j < 4; ++j)
      lats[mat][orow0 + j][ftile * 16 + sel] = acc[j] + bias;
  }
  __syncthreads();

  const int row = t >> 4, c = t & 15;
  float pi = 0.f, pj = 0.f;
#pragma unroll
  for (int q = 0; q < 8; ++q) {
    const int f = c * 8 + q;
    const float lu = lats[0][row][f];
    pi += lu * lats[1][row][f];
    pj += lu * lats[2][row][f];
  }
#pragma unroll
  for (int o = 1; o < 16; o <<= 1) {
    pi += __shfl_xor(pi, o, 64);
    pj += __shfl_xor(pj, o, 64);
  }
  if (c == 0) {
    pred_i[rowbase + row] = pi;
    pred_j[rowbase + row] = pj;
  }
}

extern "C" void kernel_launch(void* const* d_in, const int* in_sizes, int n_in,
                              void* d_out, int out_size, void* d_ws, size_t ws_size,
                              hipStream_t stream) {
  const float* user_pooled = (const float*)d_in[0];
  const float* itemj_piece = (const float*)d_in[1];
  const float* Ws1   = (const float*)d_in[2];
  const float* ws2   = (const float*)d_in[3];
  const float* Ws01  = (const float*)d_in[4];
  const float* ws02  = (const float*)d_in[5];
  const float* user_W = (const float*)d_in[6];
  const float* user_b = (const float*)d_in[7];
  const float* item_W = (const float*)d_in[8];
  const float* item_b = (const float*)d_in[9];
  const int* piece_seg = (const int*)d_in[10];
  const int* user_seg  = (const int*)d_in[11];
  const int* itemj_seg = (const int*)d_in[12];
  const int* pos_ptr   = (const int*)d_in[13];

  const int P_U  = in_sizes[10];
  const int NUNI = in_sizes[11];
  const int P_J  = in_sizes[12];

  float* ws = (float*)d_ws;
  float* v0 = ws;
  float* v1 = ws + 512;
  unsigned short* urep_h  = (unsigned short*)(ws + 1024);
  unsigned short* itemi_h = urep_h + (size_t)BS_ * D_MODEL;
  unsigned short* itemj_h = itemi_h + (size_t)BS_ * D_MODEL;
  unsigned short* uW_h    = itemj_h + (size_t)BS_ * D_MODEL;
  unsigned short* iW_h    = uW_h + FACTOR_ * D_MODEL;
  int* ib = (int*)(iW_h + FACTOR_ * D_MODEL);
  int* perm1 = ib;                 ib += P_U;
  int* perm2 = ib;                 ib += NUNI;
  int* permj = ib;                 ib += P_J;
  int* offs1 = ib;                 ib += NUNI + 1;
  int* offs2 = ib;                 ib += BS_ + 1;
  int* offsj = ib;                 ib += BS_ + 1;

  float* outf = (float*)d_out;
  float* itemi_out = outf;
  float* itemj_out = outf + (size_t)BS_ * D_MODEL;
  float* pred_i = outf + 2 * (size_t)BS_ * D_MODEL;
  float* pred_j = pred_i + BS_;

  // L1: prep (sorts + vvec + W casts)
  const int nw1 = (NUNI + WIN_ - 1) / WIN_;
  prep_all_kernel<<<nw1 + 2 + 8 + 2, 1024, 0, stream>>>(
      piece_seg, P_U, NUNI, offs1, perm1,
      user_seg, NUNI, BS_, offs2, perm2,
      itemj_seg, P_J, BS_, offsj, permj,
      Ws01, ws02, Ws1, ws2, v0, v1,
      user_W, item_W, uW_h, iW_h, nw1);

  // L2: fused pools — 512-thread blocks (8 waves) for more in-flight loads
  const int gridB = (BS_ + 7) / 8, gridC = (BS_ + 7) / 8;
  mega_pool_kernel<<<BS_ + gridB + gridC, 512, 0, stream>>>(
      user_pooled, perm1, offs1, perm2, offs2, user_seg, NUNI,
      itemj_piece, permj, offsj, v0, v1,
      urep_h, itemi_h, itemj_h, itemi_out, itemj_out, pos_ptr);

  // L3: MFMA latents + scores
  latpred_mfma_kernel<<<BS_ / 16, 256, 0, stream>>>(
      urep_h, itemi_h, itemj_h, uW_h, iW_h, user_b, item_b, pred_i, pred_j);
}

// Round 18
// 94.468 us; speedup vs baseline: 1.0180x; 1.0180x over previous
//
#include <hip/hip_runtime.h>

#define D_MODEL 512
#define D4C     128
#define DA_C    256
#define FACTOR_ 128
#define BS_     4096
#define WIN_    4096

typedef __attribute__((ext_vector_type(8))) short short8;
typedef __attribute__((ext_vector_type(4))) float f32x4;

__device__ __forceinline__ float wave_reduce_sum(float x) {
#pragma unroll
  for (int o = 32; o; o >>= 1) x += __shfl_xor(x, o, 64);
  return x;
}
__device__ __forceinline__ int wave_reduce_sum_i(int x) {
#pragma unroll
  for (int o = 32; o; o >>= 1) x += __shfl_xor(x, o, 64);
  return x;
}
__device__ __forceinline__ unsigned short f2bf(float f) {
  unsigned u = __float_as_uint(f);
  unsigned r = (u + 0x7FFF + ((u >> 16) & 1)) >> 16;   // RNE
  return (unsigned short)r;
}

// ---- L1: prep (3 windowed sorts + vvec + W bf16 casts), ONE launch (r16 verbatim) ----
__global__ __launch_bounds__(1024)
void prep_all_kernel(const int* __restrict__ seg1, int n1, int k1,
                     int* __restrict__ offs1, int* __restrict__ perm1,
                     const int* __restrict__ seg2, int n2, int k2,
                     int* __restrict__ offs2, int* __restrict__ perm2,
                     const int* __restrict__ seg3, int n3, int k3,
                     int* __restrict__ offs3, int* __restrict__ perm3,
                     const float* __restrict__ Ws01, const float* __restrict__ ws02,
                     const float* __restrict__ Ws1,  const float* __restrict__ ws2,
                     float* __restrict__ v0, float* __restrict__ v1,
                     const float* __restrict__ user_W, const float* __restrict__ item_W,
                     unsigned short* __restrict__ uW_h, unsigned short* __restrict__ iW_h,
                     int nw1) {
  __shared__ int hist[WIN_];
  __shared__ int obase[WIN_];
  __shared__ int wpre[17];
  __shared__ int below_sh[16];
  __shared__ float vred[8][128];

  const int bx = blockIdx.x, t = threadIdx.x;
  const int lane = t & 63, wid = t >> 6;
  const int nsort = nw1 + 2;

  if (bx < nsort) {
    const int* seg; int n, k, lo, hi;
    int *offs, *perm;
    if (bx < nw1)      { seg = seg1; n = n1; k = k1; offs = offs1; perm = perm1;
                         lo = bx * WIN_; hi = min(lo + WIN_, k); }
    else if (bx == nw1){ seg = seg2; n = n2; k = k2; offs = offs2; perm = perm2;
                         lo = 0; hi = k; }
    else               { seg = seg3; n = n3; k = k3; offs = offs3; perm = perm3;
                         lo = 0; hi = k; }
    const int wk = hi - lo;
    const int n4 = n >> 2;
    const int4* __restrict__ seg4 = (const int4*)seg;

    for (int i = t; i < wk; i += 1024) hist[i] = 0;
    __syncthreads();

    int below = 0;
#pragma unroll 4
    for (int i = t; i < n4; i += 1024) {
      int4 v = seg4[i];
      unsigned a = (unsigned)v.x, b = (unsigned)v.y,
               c = (unsigned)v.z, d = (unsigned)v.w;
      if (a < (unsigned)lo) below++;
      else { unsigned l = a - (unsigned)lo; if (l < (unsigned)wk) atomicAdd(&hist[l], 1); }
      if (b < (unsigned)lo) below++;
      else { unsigned l = b - (unsigned)lo; if (l < (unsigned)wk) atomicAdd(&hist[l], 1); }
      if (c < (unsigned)lo) below++;
      else { unsigned l = c - (unsigned)lo; if (l < (unsigned)wk) atomicAdd(&hist[l], 1); }
      if (d < (unsigned)lo) below++;
      else { unsigned l = d - (unsigned)lo; if (l < (unsigned)wk) atomicAdd(&hist[l], 1); }
    }
    for (int i = n4 * 4 + t; i < n; i += 1024) {
      unsigned uv = (unsigned)seg[i];
      if (uv < (unsigned)lo) below++;
      else { unsigned l = uv - (unsigned)lo;
             if (l < (unsigned)wk) atomicAdd(&hist[l], 1); }
    }
    below = wave_reduce_sum_i(below);
    if (lane == 0) below_sh[wid] = below;
    __syncthreads();
    int base = 0;
#pragma unroll
    for (int i = 0; i < 16; ++i) base += below_sh[i];

    const int per = (wk + 1023) / 1024;
    const int slo = min(t * per, wk), shi = min(slo + per, wk);
    int s = 0;
    for (int i = slo; i < shi; ++i) s += hist[i];
    int x = s;
#pragma unroll
    for (int o = 1; o < 64; o <<= 1) {
      int y = __shfl_up(x, o, 64);
      if (lane >= o) x += y;
    }
    if (lane == 63) wpre[wid] = x;
    __syncthreads();
    if (t == 0) {
      int acc = 0;
#pragma unroll
      for (int i = 0; i < 16; ++i) { int tmp = wpre[i]; wpre[i] = acc; acc += tmp; }
      wpre[16] = acc;
    }
    __syncthreads();
    int acc = base + wpre[wid] + (x - s);
    for (int i = slo; i < shi; ++i) {
      obase[i] = acc;
      offs[lo + i] = acc;
      acc += hist[i];
    }
    if (hi == k && t == 0) offs[k] = base + wpre[16];
    __syncthreads();

    for (int i = t; i < wk; i += 1024) hist[i] = 0;
    __syncthreads();
#pragma unroll 4
    for (int i = t; i < n4; i += 1024) {
      int4 v = seg4[i];
      const int rbase = i * 4;
      { unsigned l = (unsigned)v.x - (unsigned)lo;
        if (l < (unsigned)wk) { int pos = atomicAdd(&hist[l], 1); perm[obase[l] + pos] = rbase; } }
      { unsigned l = (unsigned)v.y - (unsigned)lo;
        if (l < (unsigned)wk) { int pos = atomicAdd(&hist[l], 1); perm[obase[l] + pos] = rbase + 1; } }
      { unsigned l = (unsigned)v.z - (unsigned)lo;
        if (l < (unsigned)wk) { int pos = atomicAdd(&hist[l], 1); perm[obase[l] + pos] = rbase + 2; } }
      { unsigned l = (unsigned)v.w - (unsigned)lo;
        if (l < (unsigned)wk) { int pos = atomicAdd(&hist[l], 1); perm[obase[l] + pos] = rbase + 3; } }
    }
    for (int i = n4 * 4 + t; i < n; i += 1024) {
      unsigned l = (unsigned)seg[i] - (unsigned)lo;
      if ((unsigned)seg[i] >= (unsigned)lo && l < (unsigned)wk) {
        int pos = atomicAdd(&hist[l], 1);
        perm[obase[l] + pos] = i;
      }
    }
    return;
  }

  if (bx < nsort + 8) {
    const int vb = bx - nsort;
    const int m = vb >> 2;
    const int c0 = (vb & 3) * 128;
    const float* W  = m ? Ws1 : Ws01;
    const float* w2 = m ? ws2 : ws02;
    const int col = t & 127;
    const int g = t >> 7;
    float s = 0.f;
    for (int a = g * 32; a < g * 32 + 32; ++a)
      s += w2[a] * W[a * D_MODEL + c0 + col];
    vred[g][col] = s;
    __syncthreads();
    if (t < 128) {
      float acc = 0.f;
#pragma unroll
      for (int q = 0; q < 8; ++q) acc += vred[q][t];
      (m ? v1 : v0)[c0 + t] = acc;
    }
    return;
  }

  {
    const int w = bx - (nsort + 8);
    const float4* __restrict__ src = (const float4*)(w ? item_W : user_W);
    ushort4* __restrict__ dst = (ushort4*)(w ? iW_h : uW_h);
    for (int i = t; i < FACTOR_ * D_MODEL / 4; i += 1024) {
      float4 v = src[i];
      ushort4 h;
      h.x = f2bf(v.x); h.y = f2bf(v.y); h.z = f2bf(v.z); h.w = f2bf(v.w);
      dst[i] = h;
    }
  }
}

// Pool one segment (wave gather; VALIDATED r7-r17) + optional bf16 copy.
__device__ __forceinline__ void pool_one(const float* __restrict__ X,
                                         const int* __restrict__ perm,
                                         const int* __restrict__ offs, int g, int lane,
                                         float4 va, float4 vb, float* __restrict__ out,
                                         int orow, unsigned short* __restrict__ hout) {
  const float4* __restrict__ X4 = (const float4*)X;
  const int s = offs[g], e = offs[g + 1];
  float4 a0 = make_float4(0.f, 0.f, 0.f, 0.f);
  float4 a1 = make_float4(0.f, 0.f, 0.f, 0.f);
  float z = 0.f;
  for (int p = s; p < e; ++p) {
    int row = perm[p];
    float4 x0 = X4[(size_t)row * D4C + lane * 2];
    float4 x1 = X4[(size_t)row * D4C + lane * 2 + 1];
    float d = x0.x * va.x + x0.y * va.y + x0.z * va.z + x0.w * va.w
            + x1.x * vb.x + x1.y * vb.y + x1.z * vb.z + x1.w * vb.w;
    d = wave_reduce_sum(d);
    float w = expf(d);
    z += w;
    a0.x += w * x0.x; a0.y += w * x0.y; a0.z += w * x0.z; a0.w += w * x0.w;
    a1.x += w * x1.x; a1.y += w * x1.y; a1.z += w * x1.z; a1.w += w * x1.w;
  }
  float inv = (z > 0.f) ? 1.0f / z : 0.f;
  a0.x *= inv; a0.y *= inv; a0.z *= inv; a0.w *= inv;
  a1.x *= inv; a1.y *= inv; a1.z *= inv; a1.w *= inv;
  float4* __restrict__ O4 = (float4*)out;
  O4[(size_t)orow * D4C + lane * 2]     = a0;
  O4[(size_t)orow * D4C + lane * 2 + 1] = a1;
  if (hout) {
    ushort4 h0, h1;
    h0.x = f2bf(a0.x); h0.y = f2bf(a0.y); h0.z = f2bf(a0.z); h0.w = f2bf(a0.w);
    h1.x = f2bf(a1.x); h1.y = f2bf(a1.y); h1.z = f2bf(a1.z); h1.w = f2bf(a1.w);
    ((ushort4*)hout)[(size_t)orow * D4C + lane * 2]     = h0;
    ((ushort4*)hout)[(size_t)orow * D4C + lane * 2 + 1] = h1;
  }
}

// ---- L2: mega pool — 128-thread blocks (2 waves): 100% wave-pass utilization
// for 6-row users (3 passes x 2 waves), finer scheduling granularity.
__global__ __launch_bounds__(128)
void mega_pool_kernel(const float* __restrict__ pieces,
                      const int* __restrict__ perm1, const int* __restrict__ offs1,
                      const int* __restrict__ perm2, const int* __restrict__ offs2,
                      const int* __restrict__ user_seg, int n_uni,
                      const float* __restrict__ itemj_piece,
                      const int* __restrict__ permj, const int* __restrict__ offsj,
                      const float* __restrict__ v0, const float* __restrict__ v1,
                      unsigned short* __restrict__ urep_h,
                      unsigned short* __restrict__ itemi_h,
                      unsigned short* __restrict__ itemj_h,
                      float* __restrict__ itemi_out, float* __restrict__ itemj_out,
                      const int* __restrict__ pos_ptr) {
  const int bx = blockIdx.x;
  const int t = threadIdx.x;
  const int wid = t >> 6, lane = t & 63;
  const float4* __restrict__ V0 = (const float4*)v0;

  if (bx < BS_) {
    const float4* __restrict__ V1 = (const float4*)v1;
    const float4* __restrict__ X4 = (const float4*)pieces;
    float4 va0 = V0[lane * 2], vb0 = V0[lane * 2 + 1];
    float4 va1 = V1[lane * 2], vb1 = V1[lane * 2 + 1];
    int pos = *pos_ptr;
    pos = min(max(pos, 0), n_uni - BS_);
    const int u = bx;
    const int s2 = offs2[u], e2 = offs2[u + 1];

    float4 acc0 = make_float4(0.f, 0.f, 0.f, 0.f);
    float4 acc1 = make_float4(0.f, 0.f, 0.f, 0.f);
    float zz = 0.f;
    for (int k = s2 + wid; k < e2; k += 2) {      // 2 waves: 3 passes, all busy
      const int rr = perm2[k];
      const int s1 = offs1[rr], e1 = offs1[rr + 1];
      float4 r0 = make_float4(0.f, 0.f, 0.f, 0.f);
      float4 r1 = make_float4(0.f, 0.f, 0.f, 0.f);
      float z1 = 0.f;
      for (int p = s1; p < e1; ++p) {
        int prow = perm1[p];
        float4 x0 = X4[(size_t)prow * D4C + lane * 2];
        float4 x1 = X4[(size_t)prow * D4C + lane * 2 + 1];
        float d = x0.x * va0.x + x0.y * va0.y + x0.z * va0.z + x0.w * va0.w
                + x1.x * vb0.x + x1.y * vb0.y + x1.z * vb0.z + x1.w * vb0.w;
        d = wave_reduce_sum(d);
        float w = expf(d);
        z1 += w;
        r0.x += w * x0.x; r0.y += w * x0.y; r0.z += w * x0.z; r0.w += w * x0.w;
        r1.x += w * x1.x; r1.y += w * x1.y; r1.z += w * x1.z; r1.w += w * x1.w;
      }
      float inv1 = (z1 > 0.f) ? 1.0f / z1 : 0.f;
      r0.x *= inv1; r0.y *= inv1; r0.z *= inv1; r0.w *= inv1;
      r1.x *= inv1; r1.y *= inv1; r1.z *= inv1; r1.w *= inv1;
      if (rr >= pos && rr < pos + BS_) {
        float4* __restrict__ O2 = (float4*)itemi_out;
        O2[(size_t)(rr - pos) * D4C + lane * 2]     = r0;
        O2[(size_t)(rr - pos) * D4C + lane * 2 + 1] = r1;
        ushort4 h0, h1;
        h0.x = f2bf(r0.x); h0.y = f2bf(r0.y); h0.z = f2bf(r0.z); h0.w = f2bf(r0.w);
        h1.x = f2bf(r1.x); h1.y = f2bf(r1.y); h1.z = f2bf(r1.z); h1.w = f2bf(r1.w);
        ((ushort4*)itemi_h)[(size_t)(rr - pos) * D4C + lane * 2]     = h0;
        ((ushort4*)itemi_h)[(size_t)(rr - pos) * D4C + lane * 2 + 1] = h1;
      }
      float d1 = r0.x * va1.x + r0.y * va1.y + r0.z * va1.z + r0.w * va1.w
               + r1.x * vb1.x + r1.y * vb1.y + r1.z * vb1.z + r1.w * vb1.w;
      d1 = wave_reduce_sum(d1);
      float e2w = expf(d1);
      zz += e2w;
      acc0.x += e2w * r0.x; acc0.y += e2w * r0.y;
      acc0.z += e2w * r0.z; acc0.w += e2w * r0.w;
      acc1.x += e2w * r1.x; acc1.y += e2w * r1.y;
      acc1.z += e2w * r1.z; acc1.w += e2w * r1.w;
    }
    __shared__ float4 pbuf[2][130];
    __shared__ float zbuf[2];
    pbuf[wid][lane * 2]     = acc0;
    pbuf[wid][lane * 2 + 1] = acc1;
    if (lane == 0) zbuf[wid] = zz;
    __syncthreads();
    if (wid == 0) {
      float Z = zbuf[0] + zbuf[1];
      float4 q00 = pbuf[0][lane * 2], q01 = pbuf[0][lane * 2 + 1];
      float4 q10 = pbuf[1][lane * 2], q11 = pbuf[1][lane * 2 + 1];
      float4 A0, A1;
      A0.x = q00.x + q10.x; A0.y = q00.y + q10.y;
      A0.z = q00.z + q10.z; A0.w = q00.w + q10.w;
      A1.x = q01.x + q11.x; A1.y = q01.y + q11.y;
      A1.z = q01.z + q11.z; A1.w = q01.w + q11.w;
      float inv = (Z > 0.f) ? 1.0f / Z : 0.f;
      A0.x *= inv; A0.y *= inv; A0.z *= inv; A0.w *= inv;
      A1.x *= inv; A1.y *= inv; A1.z *= inv; A1.w *= inv;
      ushort4 h0, h1;
      h0.x = f2bf(A0.x); h0.y = f2bf(A0.y); h0.z = f2bf(A0.z); h0.w = f2bf(A0.w);
      h1.x = f2bf(A1.x); h1.y = f2bf(A1.y); h1.z = f2bf(A1.z); h1.w = f2bf(A1.w);
      ((ushort4*)urep_h)[(size_t)u * D4C + lane * 2]     = h0;
      ((ushort4*)urep_h)[(size_t)u * D4C + lane * 2 + 1] = h1;
    }
    return;
  }

  const int gridB = (BS_ + 1) >> 1;    // 2 segments per 128-thread block
  float4 va = V0[lane * 2], vb = V0[lane * 2 + 1];
  if (bx < BS_ + gridB) {
    int g = (bx - BS_) * 2 + wid;
    if (g >= BS_) return;
    pool_one(itemj_piece, permj, offsj, g, lane, va, vb, itemj_out, g, itemj_h);
  } else {
    int idx = (bx - BS_ - gridB) * 2 + wid;
    if (idx >= BS_) return;
    int pos = *pos_ptr;
    pos = min(max(pos, 0), n_uni - BS_);
    int rr = pos + idx;
    if ((unsigned)user_seg[rr] < (unsigned)BS_) return;
    pool_one(pieces, perm1, offs1, rr, lane, va, vb, itemi_out, idx, itemi_h);
  }
}

// ---- L3: MFMA latents + BPR scores (VALIDATED r16, verbatim) ----
__global__ __launch_bounds__(256)
void latpred_mfma_kernel(const unsigned short* __restrict__ urep_h,
                         const unsigned short* __restrict__ itemi_h,
                         const unsigned short* __restrict__ itemj_h,
                         const unsigned short* __restrict__ uW_h,
                         const unsigned short* __restrict__ iW_h,
                         const float* __restrict__ user_b,
                         const float* __restrict__ item_b,
                         float* __restrict__ pred_i, float* __restrict__ pred_j) {
  __shared__ float lats[3][16][132];
  const int rowbase = blockIdx.x * 16;
  const int t = threadIdx.x;
  const int wave = t >> 6, lane = t & 63;
  const int sel = lane & 15;
  const int kgrp = lane >> 4;

#pragma unroll
  for (int jj = 0; jj < 6; ++jj) {
    const int job = wave * 6 + jj;
    const int mat = job >> 3;
    const int ftile = job & 7;
    const unsigned short* A = mat == 0 ? urep_h : (mat == 1 ? itemi_h : itemj_h);
    const unsigned short* W = mat == 0 ? uW_h : iW_h;
    const float* b = mat == 0 ? user_b : item_b;
    const int f = ftile * 16 + sel;
    const short8* __restrict__ Arow = (const short8*)(A + (size_t)(rowbase + sel) * D_MODEL);
    const short8* __restrict__ Wrow = (const short8*)(W + (size_t)f * D_MODEL);
    f32x4 acc = {0.f, 0.f, 0.f, 0.f};
#pragma unroll
    for (int ks = 0; ks < 16; ++ks) {
      short8 af = Arow[ks * 4 + kgrp];
      short8 bf = Wrow[ks * 4 + kgrp];
      acc = __builtin_amdgcn_mfma_f32_16x16x32_bf16(af, bf, acc, 0, 0, 0);
    }
    const float bias = b[f];
    const int orow0 = kgrp * 4;
#pragma unroll
    for (int j = 0; j < 4; ++j)
      lats[mat][orow0 + j][ftile * 16 + sel] = acc[j] + bias;
  }
  __syncthreads();

  const int row = t >> 4, c = t & 15;
  float pi = 0.f, pj = 0.f;
#pragma unroll
  for (int q = 0; q < 8; ++q) {
    const int f = c * 8 + q;
    const float lu = lats[0][row][f];
    pi += lu * lats[1][row][f];
    pj += lu * lats[2][row][f];
  }
#pragma unroll
  for (int o = 1; o < 16; o <<= 1) {
    pi += __shfl_xor(pi, o, 64);
    pj += __shfl_xor(pj, o, 64);
  }
  if (c == 0) {
    pred_i[rowbase + row] = pi;
    pred_j[rowbase + row] = pj;
  }
}

extern "C" void kernel_launch(void* const* d_in, const int* in_sizes, int n_in,
                              void* d_out, int out_size, void* d_ws, size_t ws_size,
                              hipStream_t stream) {
  const float* user_pooled = (const float*)d_in[0];
  const float* itemj_piece = (const float*)d_in[1];
  const float* Ws1   = (const float*)d_in[2];
  const float* ws2   = (const float*)d_in[3];
  const float* Ws01  = (const float*)d_in[4];
  const float* ws02  = (const float*)d_in[5];
  const float* user_W = (const float*)d_in[6];
  const float* user_b = (const float*)d_in[7];
  const float* item_W = (const float*)d_in[8];
  const float* item_b = (const float*)d_in[9];
  const int* piece_seg = (const int*)d_in[10];
  const int* user_seg  = (const int*)d_in[11];
  const int* itemj_seg = (const int*)d_in[12];
  const int* pos_ptr   = (const int*)d_in[13];

  const int P_U  = in_sizes[10];
  const int NUNI = in_sizes[11];
  const int P_J  = in_sizes[12];

  float* ws = (float*)d_ws;
  float* v0 = ws;
  float* v1 = ws + 512;
  unsigned short* urep_h  = (unsigned short*)(ws + 1024);
  unsigned short* itemi_h = urep_h + (size_t)BS_ * D_MODEL;
  unsigned short* itemj_h = itemi_h + (size_t)BS_ * D_MODEL;
  unsigned short* uW_h    = itemj_h + (size_t)BS_ * D_MODEL;
  unsigned short* iW_h    = uW_h + FACTOR_ * D_MODEL;
  int* ib = (int*)(iW_h + FACTOR_ * D_MODEL);
  int* perm1 = ib;                 ib += P_U;
  int* perm2 = ib;                 ib += NUNI;
  int* permj = ib;                 ib += P_J;
  int* offs1 = ib;                 ib += NUNI + 1;
  int* offs2 = ib;                 ib += BS_ + 1;
  int* offsj = ib;                 ib += BS_ + 1;

  float* outf = (float*)d_out;
  float* itemi_out = outf;
  float* itemj_out = outf + (size_t)BS_ * D_MODEL;
  float* pred_i = outf + 2 * (size_t)BS_ * D_MODEL;
  float* pred_j = pred_i + BS_;

  // L1: prep (sorts + vvec + W casts)
  const int nw1 = (NUNI + WIN_ - 1) / WIN_;
  prep_all_kernel<<<nw1 + 2 + 8 + 2, 1024, 0, stream>>>(
      piece_seg, P_U, NUNI, offs1, perm1,
      user_seg, NUNI, BS_, offs2, perm2,
      itemj_seg, P_J, BS_, offsj, permj,
      Ws01, ws02, Ws1, ws2, v0, v1,
      user_W, item_W, uW_h, iW_h, nw1);

  // L2: fused pools — 128-thread blocks (2 waves)
  const int gridB = (BS_ + 1) / 2, gridC = (BS_ + 1) / 2;
  mega_pool_kernel<<<BS_ + gridB + gridC, 128, 0, stream>>>(
      user_pooled, perm1, offs1, perm2, offs2, user_seg, NUNI,
      itemj_piece, permj, offsj, v0, v1,
      urep_h, itemi_h, itemj_h, itemi_out, itemj_out, pos_ptr);

  // L3: MFMA latents + scores
  latpred_mfma_kernel<<<BS_ / 16, 256, 0, stream>>>(
      urep_h, itemi_h, itemj_h, uW_h, iW_h, user_b, item_b, pred_i, pred_j);
}

// Round 19
// 91.241 us; speedup vs baseline: 1.0540x; 1.0354x over previous
//
#include <hip/hip_runtime.h>

#define D_MODEL 512
#define D4C     128
#define DA_C    256
#define FACTOR_ 128
#define BS_     4096
#define WIN_    4096

typedef __attribute__((ext_vector_type(8))) short short8;
typedef __attribute__((ext_vector_type(4))) float f32x4;

__device__ __forceinline__ float wave_reduce_sum(float x) {
#pragma unroll
  for (int o = 32; o; o >>= 1) x += __shfl_xor(x, o, 64);
  return x;
}
__device__ __forceinline__ int wave_reduce_sum_i(int x) {
#pragma unroll
  for (int o = 32; o; o >>= 1) x += __shfl_xor(x, o, 64);
  return x;
}
__device__ __forceinline__ unsigned short f2bf(float f) {
  unsigned u = __float_as_uint(f);
  unsigned r = (u + 0x7FFF + ((u >> 16) & 1)) >> 16;   // RNE
  return (unsigned short)r;
}

// ---- L1: prep (3 windowed sorts + vvec + W bf16 casts), ONE launch ----
__global__ __launch_bounds__(1024)
void prep_all_kernel(const int* __restrict__ seg1, int n1, int k1,
                     int* __restrict__ offs1, int* __restrict__ perm1,
                     const int* __restrict__ seg2, int n2, int k2,
                     int* __restrict__ offs2, int* __restrict__ perm2,
                     const int* __restrict__ seg3, int n3, int k3,
                     int* __restrict__ offs3, int* __restrict__ perm3,
                     const float* __restrict__ Ws01, const float* __restrict__ ws02,
                     const float* __restrict__ Ws1,  const float* __restrict__ ws2,
                     float* __restrict__ v0, float* __restrict__ v1,
                     const float* __restrict__ user_W, const float* __restrict__ item_W,
                     unsigned short* __restrict__ uW_h, unsigned short* __restrict__ iW_h,
                     int nw1) {
  __shared__ int hist[WIN_];
  __shared__ int obase[WIN_];
  __shared__ int wpre[17];
  __shared__ int below_sh[16];
  __shared__ float vred[8][128];

  const int bx = blockIdx.x, t = threadIdx.x;
  const int lane = t & 63, wid = t >> 6;
  const int nsort = nw1 + 2;

  if (bx < nsort) {
    const int* seg; int n, k, lo, hi;
    int *offs, *perm;
    if (bx < nw1)      { seg = seg1; n = n1; k = k1; offs = offs1; perm = perm1;
                         lo = bx * WIN_; hi = min(lo + WIN_, k); }
    else if (bx == nw1){ seg = seg2; n = n2; k = k2; offs = offs2; perm = perm2;
                         lo = 0; hi = k; }
    else               { seg = seg3; n = n3; k = k3; offs = offs3; perm = perm3;
                         lo = 0; hi = k; }
    const int wk = hi - lo;
    const int n4 = n >> 2;
    const int4* __restrict__ seg4 = (const int4*)seg;

    for (int i = t; i < wk; i += 1024) hist[i] = 0;
    __syncthreads();

    int below = 0;
#pragma unroll 4
    for (int i = t; i < n4; i += 1024) {
      int4 v = seg4[i];
      unsigned a = (unsigned)v.x, b = (unsigned)v.y,
               c = (unsigned)v.z, d = (unsigned)v.w;
      if (a < (unsigned)lo) below++;
      else { unsigned l = a - (unsigned)lo; if (l < (unsigned)wk) atomicAdd(&hist[l], 1); }
      if (b < (unsigned)lo) below++;
      else { unsigned l = b - (unsigned)lo; if (l < (unsigned)wk) atomicAdd(&hist[l], 1); }
      if (c < (unsigned)lo) below++;
      else { unsigned l = c - (unsigned)lo; if (l < (unsigned)wk) atomicAdd(&hist[l], 1); }
      if (d < (unsigned)lo) below++;
      else { unsigned l = d - (unsigned)lo; if (l < (unsigned)wk) atomicAdd(&hist[l], 1); }
    }
    for (int i = n4 * 4 + t; i < n; i += 1024) {
      unsigned uv = (unsigned)seg[i];
      if (uv < (unsigned)lo) below++;
      else { unsigned l = uv - (unsigned)lo;
             if (l < (unsigned)wk) atomicAdd(&hist[l], 1); }
    }
    below = wave_reduce_sum_i(below);
    if (lane == 0) below_sh[wid] = below;
    __syncthreads();
    int base = 0;
#pragma unroll
    for (int i = 0; i < 16; ++i) base += below_sh[i];

    const int per = (wk + 1023) / 1024;
    const int slo = min(t * per, wk), shi = min(slo + per, wk);
    int s = 0;
    for (int i = slo; i < shi; ++i) s += hist[i];
    int x = s;
#pragma unroll
    for (int o = 1; o < 64; o <<= 1) {
      int y = __shfl_up(x, o, 64);
      if (lane >= o) x += y;
    }
    if (lane == 63) wpre[wid] = x;
    __syncthreads();
    if (t == 0) {
      int acc = 0;
#pragma unroll
      for (int i = 0; i < 16; ++i) { int tmp = wpre[i]; wpre[i] = acc; acc += tmp; }
      wpre[16] = acc;
    }
    __syncthreads();
    int acc = base + wpre[wid] + (x - s);
    for (int i = slo; i < shi; ++i) {
      obase[i] = acc;
      offs[lo + i] = acc;
      acc += hist[i];
    }
    if (hi == k && t == 0) offs[k] = base + wpre[16];
    __syncthreads();

    for (int i = t; i < wk; i += 1024) hist[i] = 0;
    __syncthreads();
#pragma unroll 4
    for (int i = t; i < n4; i += 1024) {
      int4 v = seg4[i];
      const int rbase = i * 4;
      { unsigned l = (unsigned)v.x - (unsigned)lo;
        if (l < (unsigned)wk) { int pos = atomicAdd(&hist[l], 1); perm[obase[l] + pos] = rbase; } }
      { unsigned l = (unsigned)v.y - (unsigned)lo;
        if (l < (unsigned)wk) { int pos = atomicAdd(&hist[l], 1); perm[obase[l] + pos] = rbase + 1; } }
      { unsigned l = (unsigned)v.z - (unsigned)lo;
        if (l < (unsigned)wk) { int pos = atomicAdd(&hist[l], 1); perm[obase[l] + pos] = rbase + 2; } }
      { unsigned l = (unsigned)v.w - (unsigned)lo;
        if (l < (unsigned)wk) { int pos = atomicAdd(&hist[l], 1); perm[obase[l] + pos] = rbase + 3; } }
    }
    for (int i = n4 * 4 + t; i < n; i += 1024) {
      unsigned l = (unsigned)seg[i] - (unsigned)lo;
      if ((unsigned)seg[i] >= (unsigned)lo && l < (unsigned)wk) {
        int pos = atomicAdd(&hist[l], 1);
        perm[obase[l] + pos] = i;
      }
    }
    return;
  }

  if (bx < nsort + 8) {
    const int vb = bx - nsort;
    const int m = vb >> 2;
    const int c0 = (vb & 3) * 128;
    const float* W  = m ? Ws1 : Ws01;
    const float* w2 = m ? ws2 : ws02;
    const int col = t & 127;
    const int g = t >> 7;
    float s = 0.f;
    for (int a = g * 32; a < g * 32 + 32; ++a)
      s += w2[a] * W[a * D_MODEL + c0 + col];
    vred[g][col] = s;
    __syncthreads();
    if (t < 128) {
      float acc = 0.f;
#pragma unroll
      for (int q = 0; q < 8; ++q) acc += vred[q][t];
      (m ? v1 : v0)[c0 + t] = acc;
    }
    return;
  }

  {
    const int w = bx - (nsort + 8);
    const float4* __restrict__ src = (const float4*)(w ? item_W : user_W);
    ushort4* __restrict__ dst = (ushort4*)(w ? iW_h : uW_h);
    for (int i = t; i < FACTOR_ * D_MODEL / 4; i += 1024) {
      float4 v = src[i];
      ushort4 h;
      h.x = f2bf(v.x); h.y = f2bf(v.y); h.z = f2bf(v.z); h.w = f2bf(v.w);
      dst[i] = h;
    }
  }
}

// Pool one segment (wave gather; VALIDATED r7-r16) + optional bf16 copy.
__device__ __forceinline__ void pool_one(const float* __restrict__ X,
                                         const int* __restrict__ perm,
                                         const int* __restrict__ offs, int g, int lane,
                                         float4 va, float4 vb, float* __restrict__ out,
                                         int orow, unsigned short* __restrict__ hout) {
  const float4* __restrict__ X4 = (const float4*)X;
  const int s = offs[g], e = offs[g + 1];
  float4 a0 = make_float4(0.f, 0.f, 0.f, 0.f);
  float4 a1 = make_float4(0.f, 0.f, 0.f, 0.f);
  float z = 0.f;
  for (int p = s; p < e; ++p) {
    int row = perm[p];
    float4 x0 = X4[(size_t)row * D4C + lane * 2];
    float4 x1 = X4[(size_t)row * D4C + lane * 2 + 1];
    float d = x0.x * va.x + x0.y * va.y + x0.z * va.z + x0.w * va.w
            + x1.x * vb.x + x1.y * vb.y + x1.z * vb.z + x1.w * vb.w;
    d = wave_reduce_sum(d);
    float w = expf(d);
    z += w;
    a0.x += w * x0.x; a0.y += w * x0.y; a0.z += w * x0.z; a0.w += w * x0.w;
    a1.x += w * x1.x; a1.y += w * x1.y; a1.z += w * x1.z; a1.w += w * x1.w;
  }
  float inv = (z > 0.f) ? 1.0f / z : 0.f;
  a0.x *= inv; a0.y *= inv; a0.z *= inv; a0.w *= inv;
  a1.x *= inv; a1.y *= inv; a1.z *= inv; a1.w *= inv;
  float4* __restrict__ O4 = (float4*)out;
  O4[(size_t)orow * D4C + lane * 2]     = a0;
  O4[(size_t)orow * D4C + lane * 2 + 1] = a1;
  if (hout) {
    ushort4 h0, h1;
    h0.x = f2bf(a0.x); h0.y = f2bf(a0.y); h0.z = f2bf(a0.z); h0.w = f2bf(a0.w);
    h1.x = f2bf(a1.x); h1.y = f2bf(a1.y); h1.z = f2bf(a1.z); h1.w = f2bf(a1.w);
    ((ushort4*)hout)[(size_t)orow * D4C + lane * 2]     = h0;
    ((ushort4*)hout)[(size_t)orow * D4C + lane * 2 + 1] = h1;
  }
}

// ---- L2: mega pool (r16 champion config: 256 threads, 4 waves) ----
__global__ __launch_bounds__(256)
void mega_pool_kernel(const float* __restrict__ pieces,
                      const int* __restrict__ perm1, const int* __restrict__ offs1,
                      const int* __restrict__ perm2, const int* __restrict__ offs2,
                      const int* __restrict__ user_seg, int n_uni,
                      const float* __restrict__ itemj_piece,
                      const int* __restrict__ permj, const int* __restrict__ offsj,
                      const float* __restrict__ v0, const float* __restrict__ v1,
                      unsigned short* __restrict__ urep_h,
                      unsigned short* __restrict__ itemi_h,
                      unsigned short* __restrict__ itemj_h,
                      float* __restrict__ itemi_out, float* __restrict__ itemj_out,
                      const int* __restrict__ pos_ptr) {
  const int bx = blockIdx.x;
  const int t = threadIdx.x;
  const int wid = t >> 6, lane = t & 63;
  const float4* __restrict__ V0 = (const float4*)v0;

  if (bx < BS_) {
    const float4* __restrict__ V1 = (const float4*)v1;
    const float4* __restrict__ X4 = (const float4*)pieces;
    float4 va0 = V0[lane * 2], vb0 = V0[lane * 2 + 1];
    float4 va1 = V1[lane * 2], vb1 = V1[lane * 2 + 1];
    int pos = *pos_ptr;
    pos = min(max(pos, 0), n_uni - BS_);
    const int u = bx;
    const int s2 = offs2[u], e2 = offs2[u + 1];

    float4 acc0 = make_float4(0.f, 0.f, 0.f, 0.f);
    float4 acc1 = make_float4(0.f, 0.f, 0.f, 0.f);
    float zz = 0.f;
    for (int k = s2 + wid; k < e2; k += 4) {
      const int rr = perm2[k];
      const int s1 = offs1[rr], e1 = offs1[rr + 1];
      float4 r0 = make_float4(0.f, 0.f, 0.f, 0.f);
      float4 r1 = make_float4(0.f, 0.f, 0.f, 0.f);
      float z1 = 0.f;
      for (int p = s1; p < e1; ++p) {
        int prow = perm1[p];
        float4 x0 = X4[(size_t)prow * D4C + lane * 2];
        float4 x1 = X4[(size_t)prow * D4C + lane * 2 + 1];
        float d = x0.x * va0.x + x0.y * va0.y + x0.z * va0.z + x0.w * va0.w
                + x1.x * vb0.x + x1.y * vb0.y + x1.z * vb0.z + x1.w * vb0.w;
        d = wave_reduce_sum(d);
        float w = expf(d);
        z1 += w;
        r0.x += w * x0.x; r0.y += w * x0.y; r0.z += w * x0.z; r0.w += w * x0.w;
        r1.x += w * x1.x; r1.y += w * x1.y; r1.z += w * x1.z; r1.w += w * x1.w;
      }
      float inv1 = (z1 > 0.f) ? 1.0f / z1 : 0.f;
      r0.x *= inv1; r0.y *= inv1; r0.z *= inv1; r0.w *= inv1;
      r1.x *= inv1; r1.y *= inv1; r1.z *= inv1; r1.w *= inv1;
      if (rr >= pos && rr < pos + BS_) {
        float4* __restrict__ O2 = (float4*)itemi_out;
        O2[(size_t)(rr - pos) * D4C + lane * 2]     = r0;
        O2[(size_t)(rr - pos) * D4C + lane * 2 + 1] = r1;
        ushort4 h0, h1;
        h0.x = f2bf(r0.x); h0.y = f2bf(r0.y); h0.z = f2bf(r0.z); h0.w = f2bf(r0.w);
        h1.x = f2bf(r1.x); h1.y = f2bf(r1.y); h1.z = f2bf(r1.z); h1.w = f2bf(r1.w);
        ((ushort4*)itemi_h)[(size_t)(rr - pos) * D4C + lane * 2]     = h0;
        ((ushort4*)itemi_h)[(size_t)(rr - pos) * D4C + lane * 2 + 1] = h1;
      }
      float d1 = r0.x * va1.x + r0.y * va1.y + r0.z * va1.z + r0.w * va1.w
               + r1.x * vb1.x + r1.y * vb1.y + r1.z * vb1.z + r1.w * vb1.w;
      d1 = wave_reduce_sum(d1);
      float e2w = expf(d1);
      zz += e2w;
      acc0.x += e2w * r0.x; acc0.y += e2w * r0.y;
      acc0.z += e2w * r0.z; acc0.w += e2w * r0.w;
      acc1.x += e2w * r1.x; acc1.y += e2w * r1.y;
      acc1.z += e2w * r1.z; acc1.w += e2w * r1.w;
    }
    __shared__ float4 pbuf[4][130];
    __shared__ float zbuf[4];
    pbuf[wid][lane * 2]     = acc0;
    pbuf[wid][lane * 2 + 1] = acc1;
    if (lane == 0) zbuf[wid] = zz;
    __syncthreads();
    if (wid == 0) {
      float4 A0 = make_float4(0.f, 0.f, 0.f, 0.f);
      float4 A1 = make_float4(0.f, 0.f, 0.f, 0.f);
      float Z = zbuf[0] + zbuf[1] + zbuf[2] + zbuf[3];
#pragma unroll
      for (int w = 0; w < 4; ++w) {
        float4 p0 = pbuf[w][lane * 2], p1 = pbuf[w][lane * 2 + 1];
        A0.x += p0.x; A0.y += p0.y; A0.z += p0.z; A0.w += p0.w;
        A1.x += p1.x; A1.y += p1.y; A1.z += p1.z; A1.w += p1.w;
      }
      float inv = (Z > 0.f) ? 1.0f / Z : 0.f;
      A0.x *= inv; A0.y *= inv; A0.z *= inv; A0.w *= inv;
      A1.x *= inv; A1.y *= inv; A1.z *= inv; A1.w *= inv;
      ushort4 h0, h1;
      h0.x = f2bf(A0.x); h0.y = f2bf(A0.y); h0.z = f2bf(A0.z); h0.w = f2bf(A0.w);
      h1.x = f2bf(A1.x); h1.y = f2bf(A1.y); h1.z = f2bf(A1.z); h1.w = f2bf(A1.w);
      ((ushort4*)urep_h)[(size_t)u * D4C + lane * 2]     = h0;
      ((ushort4*)urep_h)[(size_t)u * D4C + lane * 2 + 1] = h1;
    }
    return;
  }

  const int gridB = (BS_ + 3) >> 2;
  float4 va = V0[lane * 2], vb = V0[lane * 2 + 1];
  if (bx < BS_ + gridB) {
    int g = (bx - BS_) * 4 + wid;
    if (g >= BS_) return;
    pool_one(itemj_piece, permj, offsj, g, lane, va, vb, itemj_out, g, itemj_h);
  } else {
    int idx = (bx - BS_ - gridB) * 4 + wid;
    if (idx >= BS_) return;
    int pos = *pos_ptr;
    pos = min(max(pos, 0), n_uni - BS_);
    int rr = pos + idx;
    if ((unsigned)user_seg[rr] < (unsigned)BS_) return;
    pool_one(pieces, perm1, offs1, rr, lane, va, vb, itemi_out, idx, itemi_h);
  }
}

// ---- L3: MFMA latents + BPR scores (VALIDATED r16, verbatim) ----
__global__ __launch_bounds__(256)
void latpred_mfma_kernel(const unsigned short* __restrict__ urep_h,
                         const unsigned short* __restrict__ itemi_h,
                         const unsigned short* __restrict__ itemj_h,
                         const unsigned short* __restrict__ uW_h,
                         const unsigned short* __restrict__ iW_h,
                         const float* __restrict__ user_b,
                         const float* __restrict__ item_b,
                         float* __restrict__ pred_i, float* __restrict__ pred_j) {
  __shared__ float lats[3][16][132];
  const int rowbase = blockIdx.x * 16;
  const int t = threadIdx.x;
  const int wave = t >> 6, lane = t & 63;
  const int sel = lane & 15;
  const int kgrp = lane >> 4;

#pragma unroll
  for (int jj = 0; jj < 6; ++jj) {
    const int job = wave * 6 + jj;
    const int mat = job >> 3;
    const int ftile = job & 7;
    const unsigned short* A = mat == 0 ? urep_h : (mat == 1 ? itemi_h : itemj_h);
    const unsigned short* W = mat == 0 ? uW_h : iW_h;
    const float* b = mat == 0 ? user_b : item_b;
    const int f = ftile * 16 + sel;
    const short8* __restrict__ Arow = (const short8*)(A + (size_t)(rowbase + sel) * D_MODEL);
    const short8* __restrict__ Wrow = (const short8*)(W + (size_t)f * D_MODEL);
    f32x4 acc = {0.f, 0.f, 0.f, 0.f};
#pragma unroll
    for (int ks = 0; ks < 16; ++ks) {
      short8 af = Arow[ks * 4 + kgrp];
      short8 bf = Wrow[ks * 4 + kgrp];
      acc = __builtin_amdgcn_mfma_f32_16x16x32_bf16(af, bf, acc, 0, 0, 0);
    }
    const float bias = b[f];
    const int orow0 = kgrp * 4;
#pragma unroll
    for (int j = 0; j < 4; ++j)
      lats[mat][orow0 + j][ftile * 16 + sel] = acc[j] + bias;
  }
  __syncthreads();

  const int row = t >> 4, c = t & 15;
  float pi = 0.f, pj = 0.f;
#pragma unroll
  for (int q = 0; q < 8; ++q) {
    const int f = c * 8 + q;
    const float lu = lats[0][row][f];
    pi += lu * lats[1][row][f];
    pj += lu * lats[2][row][f];
  }
#pragma unroll
  for (int o = 1; o < 16; o <<= 1) {
    pi += __shfl_xor(pi, o, 64);
    pj += __shfl_xor(pj, o, 64);
  }
  if (c == 0) {
    pred_i[rowbase + row] = pi;
    pred_j[rowbase + row] = pj;
  }
}

extern "C" void kernel_launch(void* const* d_in, const int* in_sizes, int n_in,
                              void* d_out, int out_size, void* d_ws, size_t ws_size,
                              hipStream_t stream) {
  const float* user_pooled = (const float*)d_in[0];
  const float* itemj_piece = (const float*)d_in[1];
  const float* Ws1   = (const float*)d_in[2];
  const float* ws2   = (const float*)d_in[3];
  const float* Ws01  = (const float*)d_in[4];
  const float* ws02  = (const float*)d_in[5];
  const float* user_W = (const float*)d_in[6];
  const float* user_b = (const float*)d_in[7];
  const float* item_W = (const float*)d_in[8];
  const float* item_b = (const float*)d_in[9];
  const int* piece_seg = (const int*)d_in[10];
  const int* user_seg  = (const int*)d_in[11];
  const int* itemj_seg = (const int*)d_in[12];
  const int* pos_ptr   = (const int*)d_in[13];

  const int P_U  = in_sizes[10];
  const int NUNI = in_sizes[11];
  const int P_J  = in_sizes[12];

  float* ws = (float*)d_ws;
  float* v0 = ws;
  float* v1 = ws + 512;
  unsigned short* urep_h  = (unsigned short*)(ws + 1024);
  unsigned short* itemi_h = urep_h + (size_t)BS_ * D_MODEL;
  unsigned short* itemj_h = itemi_h + (size_t)BS_ * D_MODEL;
  unsigned short* uW_h    = itemj_h + (size_t)BS_ * D_MODEL;
  unsigned short* iW_h    = uW_h + FACTOR_ * D_MODEL;
  int* ib = (int*)(iW_h + FACTOR_ * D_MODEL);
  int* perm1 = ib;                 ib += P_U;
  int* perm2 = ib;                 ib += NUNI;
  int* permj = ib;                 ib += P_J;
  int* offs1 = ib;                 ib += NUNI + 1;
  int* offs2 = ib;                 ib += BS_ + 1;
  int* offsj = ib;                 ib += BS_ + 1;

  float* outf = (float*)d_out;
  float* itemi_out = outf;
  float* itemj_out = outf + (size_t)BS_ * D_MODEL;
  float* pred_i = outf + 2 * (size_t)BS_ * D_MODEL;
  float* pred_j = pred_i + BS_;

  // L1: prep (sorts + vvec + W casts)
  const int nw1 = (NUNI + WIN_ - 1) / WIN_;
  prep_all_kernel<<<nw1 + 2 + 8 + 2, 1024, 0, stream>>>(
      piece_seg, P_U, NUNI, offs1, perm1,
      user_seg, NUNI, BS_, offs2, perm2,
      itemj_seg, P_J, BS_, offsj, permj,
      Ws01, ws02, Ws1, ws2, v0, v1,
      user_W, item_W, uW_h, iW_h, nw1);

  // L2: fused pools — 256-thread blocks (4 waves): empirical optimum (r13/r17/r18)
  const int gridB = (BS_ + 3) / 4, gridC = (BS_ + 3) / 4;
  mega_pool_kernel<<<BS_ + gridB + gridC, 256, 0, stream>>>(
      user_pooled, perm1, offs1, perm2, offs2, user_seg, NUNI,
      itemj_piece, permj, offsj, v0, v1,
      urep_h, itemi_h, itemj_h, itemi_out, itemj_out, pos_ptr);

  // L3: MFMA latents + scores
  latpred_mfma_kernel<<<BS_ / 16, 256, 0, stream>>>(
      urep_h, itemi_h, itemj_h, uW_h, iW_h, user_b, item_b, pred_i, pred_j);
}